// Round 4
// baseline (379.100 us; speedup 1.0000x reference)
//
#include <hip/hip_runtime.h>

// Problem constants (match reference)
constexpr int Bx = 64;
constexpr int Lx = 1024;
constexpr int Dx = 1024;
constexpr int Sx = 32;

constexpr int DC   = 256;             // D-columns per block (4 chunks)
constexpr int NCH  = Dx / DC;         // 4
constexpr int ROWS = Sx + 1;          // row 0 = trash row for label 0
constexpr int NBLK = Bx * NCH;        // 256 blocks = 1/CU
constexpr int PREF = 8;               // rolling loads in flight per wave

// ---------------------------------------------------------------------------
// Kernel 0: counting-sort token indices by label, once per batch.
//  spack_g[b][pos] = (label<<16)|l, labels ascending. Also writes wcnt.
// ---------------------------------------------------------------------------
__global__ __launch_bounds__(1024) void sort_kernel(
    const int* __restrict__ attrs,   // [B][L]
    int* __restrict__ spack_g,       // [B][L]
    int* __restrict__ wcnt)          // [B][S]
{
    __shared__ int hist[ROWS];
    __shared__ int cursor[ROWS];
    const int b   = blockIdx.x;
    const int tid = threadIdx.x;

    if (tid < ROWS) hist[tid] = 0;
    __syncthreads();
    const int a = attrs[b * Lx + tid];     // tid == token index (L == blockDim)
    atomicAdd(&hist[a], 1);
    __syncthreads();
    if (tid < 64) {                        // exclusive scan over 33 bins
        const int h = (tid < ROWS) ? hist[tid] : 0;
        int v = h;
        #pragma unroll
        for (int off = 1; off < 64; off <<= 1) {
            const int u = __shfl_up(v, off, 64);
            if (tid >= off) v += u;
        }
        if (tid < ROWS) cursor[tid] = v - h;
    }
    __syncthreads();
    const int pos = atomicAdd(&cursor[a], 1);
    spack_g[b * Lx + pos] = (a << 16) | tid;
    if (tid >= 1 && tid <= Sx) wcnt[b * Sx + (tid - 1)] = hist[tid];
}

// ---------------------------------------------------------------------------
// Kernel 1: per (batch, D-chunk) block, 1024 threads = 16 waves, 1 block/CU.
//  Wave owns 64 sorted tokens; packs live in one VGPR (pv), extracted with
//  readlane -> SGPR. Rolling 8-deep UNCONDITIONAL prefetch (label-0 rows
//  load too and drain into trash row 0): static load count lets the compiler
//  emit partial vmcnt(N) waits instead of vmcnt(0) -- R3's conditional loads
//  defeated that. launch_bounds(1024,4): VGPR<=128, no spills (R3's (,8)
//  forced <=64 and likely spilled buf[]).
//  Equal labels adjacent -> accumulate in a float4, flush to LDS acc[label]
//  only at label boundaries (scalar branch, ~33 per wave total).
// ---------------------------------------------------------------------------
__global__ __launch_bounds__(1024, 4) void seg_dot_kernel(
    const float* __restrict__ text,    // [B][L][D]
    const float* __restrict__ vgs,     // [B][S][D]
    const int*   __restrict__ spack_g, // [B][L]
    float* __restrict__ pnum,          // [NBLK][S]
    float* __restrict__ pns2,          // [NBLK][S]
    float* __restrict__ pnv2)          // [NBLK][S]
{
    __shared__ float acc[ROWS * DC];   // 33 KB

    const int tid    = threadIdx.x;
    const int bid    = blockIdx.x;
    const int b      = bid >> 2;
    const int dchunk = bid & 3;
    const int d0     = dchunk * DC;
    const int w      = tid >> 6;
    const int lane   = tid & 63;
    const int coloff = d0 + lane * 4;

    for (int i = tid; i < ROWS * DC; i += 1024) acc[i] = 0.0f;

    // all 64 packs for this wave: one coalesced load, kept in a VGPR
    const int pv = spack_g[b * Lx + w * 64 + lane];

    const float* __restrict__ text_b = text + (size_t)b * Lx * Dx;

    __syncthreads();   // acc zeroed

    float4 buf[PREF];
    int    pk[PREF];

    #pragma unroll
    for (int j = 0; j < PREF; ++j) {           // prologue: fill the pipe
        const int p = __builtin_amdgcn_readlane(pv, j);
        pk[j] = p;
        buf[j] = *(const float4*)(text_b + (size_t)(p & 0xffff) * Dx + coloff);
    }

    float4 a4  = make_float4(0.f, 0.f, 0.f, 0.f);
    int    cur = 0;

    #pragma unroll
    for (int j = 0; j < 64; ++j) {
        const int    slot = j & (PREF - 1);
        const int    s    = pk[slot] >> 16;
        const float4 vv   = buf[slot];         // waits on this slot only
        if (j + PREF < 64) {                   // reissue into freed slot
            const int pn = __builtin_amdgcn_readlane(pv, j + PREF);
            pk[slot] = pn;
            buf[slot] =
                *(const float4*)(text_b + (size_t)(pn & 0xffff) * Dx + coloff);
        }
        if (s != cur) {                        // scalar branch: flush boundary
            atomicAdd(&acc[cur * DC + lane * 4 + 0], a4.x);
            atomicAdd(&acc[cur * DC + lane * 4 + 1], a4.y);
            atomicAdd(&acc[cur * DC + lane * 4 + 2], a4.z);
            atomicAdd(&acc[cur * DC + lane * 4 + 3], a4.w);
            a4  = make_float4(0.f, 0.f, 0.f, 0.f);
            cur = s;
        }
        a4.x += vv.x; a4.y += vv.y;            // label 0 drains into row 0
        a4.z += vv.z; a4.w += vv.w;
    }
    atomicAdd(&acc[cur * DC + lane * 4 + 0], a4.x);
    atomicAdd(&acc[cur * DC + lane * 4 + 1], a4.y);
    atomicAdd(&acc[cur * DC + lane * 4 + 2], a4.z);
    atomicAdd(&acc[cur * DC + lane * 4 + 3], a4.w);
    __syncthreads();

    // Phase B: per-label partials for this d-chunk (additive across chunks)
    #pragma unroll
    for (int si = 0; si < 2; ++si) {
        const int s = w + si * 16;             // label 0..31
        const float4 vv =
            *(const float4*)(vgs + (size_t)(b * Sx + s) * Dx + d0 + lane * 4);
        const float4 m = *(const float4*)(&acc[(s + 1) * DC + lane * 4]);
        float num = m.x * vv.x + m.y * vv.y + m.z * vv.z + m.w * vv.w;
        float ns2 = m.x * m.x + m.y * m.y + m.z * m.z + m.w * m.w;
        float nv2 = vv.x * vv.x + vv.y * vv.y + vv.z * vv.z + vv.w * vv.w;
        #pragma unroll
        for (int off = 32; off > 0; off >>= 1) {
            num += __shfl_xor(num, off, 64);
            ns2 += __shfl_xor(ns2, off, 64);
            nv2 += __shfl_xor(nv2, off, 64);
        }
        if (lane == 0) {
            const int idx = bid * Sx + s;
            pnum[idx] = num;
            pns2[idx] = ns2;
            pnv2[idx] = nv2;
        }
    }
}

// ---------------------------------------------------------------------------
// Kernel 2: fold the 4 D-chunk partials per (b,s), torch cosine eps
// semantics, reduce to the scalar loss.
//   cos = num / max(||V|| * ||seg_sum||, eps*cnt)
// ---------------------------------------------------------------------------
__global__ __launch_bounds__(256) void finalize_kernel(
    const float* __restrict__ pnum, const float* __restrict__ pns2,
    const float* __restrict__ pnv2, const int* __restrict__ wcnt,
    float* __restrict__ out)
{
    const int tid = threadIdx.x;
    float lsum = 0.0f;
    #pragma unroll
    for (int k = 0; k < (Bx * Sx) / 256; ++k) {   // 8 pairs/thread
        const int p = k * 256 + tid;              // (b,s) flat index
        const int b = p >> 5;
        const int s = p & 31;
        float num = 0.f, ns2 = 0.f, nv2 = 0.f;
        #pragma unroll
        for (int dc = 0; dc < NCH; ++dc) {
            const int idx = (b * NCH + dc) * Sx + s;
            num += pnum[idx];
            ns2 += pns2[idx];
            nv2 += pnv2[idx];
        }
        const float cnt   = (float)wcnt[p];
        const float denom = fmaxf(sqrtf(nv2) * sqrtf(ns2), 1e-8f * cnt);
        lsum += num / denom;
    }
    #pragma unroll
    for (int off = 32; off > 0; off >>= 1) lsum += __shfl_xor(lsum, off, 64);

    __shared__ float red[4];
    if ((tid & 63) == 0) red[tid >> 6] = lsum;
    __syncthreads();
    if (tid == 0) {
        const float total = red[0] + red[1] + red[2] + red[3];
        out[0] = 1.0f - total * (1.0f / (float)(Bx * Sx));
    }
}

// ---------------------------------------------------------------------------
extern "C" void kernel_launch(void* const* d_in, const int* in_sizes, int n_in,
                              void* d_out, int out_size, void* d_ws, size_t ws_size,
                              hipStream_t stream) {
    const int*   attrs = (const int*)d_in[0];
    const float* text  = (const float*)d_in[1];
    const float* vgs   = (const float*)d_in[2];
    float* out = (float*)d_out;

    int*   spack = (int*)d_ws;                   // 64*1024 i32 = 256 KB
    float* pnum  = (float*)(spack + Bx * Lx);    // 256*32 f32 = 32 KB
    float* pns2  = pnum + NBLK * Sx;             // 32 KB
    float* pnv2  = pns2 + NBLK * Sx;             // 32 KB
    int*   wcnt  = (int*)(pnv2 + NBLK * Sx);     // 8 KB

    sort_kernel<<<Bx, 1024, 0, stream>>>(attrs, spack, wcnt);
    seg_dot_kernel<<<NBLK, 1024, 0, stream>>>(text, vgs, spack,
                                              pnum, pns2, pnv2);
    finalize_kernel<<<1, 256, 0, stream>>>(pnum, pns2, pnv2, wcnt, out);
}